// Round 10
// baseline (263.338 us; speedup 1.0000x reference)
//
#include <hip/hip_runtime.h>

// Problem constants (fixed by the reference)
constexpr int N = 50000;
constexpr int E = 800000;
constexpr int G = 1024;

constexpr int NBUCK = (N + 127) / 128;     // 391 buckets of 128 nodes
constexpr int CHUNK = 4096;                // edges per pass-1 block
constexpr int NBLK  = (E + CHUNK - 1) / CHUNK;  // 196
constexpr int SC_N  = NBUCK * NBLK;        // 76636 histogram entries
constexpr int SCB   = (SC_N + 255) / 256;  // 300 scan blocks
constexpr int BCAP  = 4096;                // bucket capacity (mean 2046, +45 sigma)

typedef __attribute__((ext_vector_type(8))) short short8;
typedef __attribute__((ext_vector_type(4))) float f32x4;

__device__ __forceinline__ unsigned short f2bf(float x) {
    union { float f; unsigned u; } v; v.f = x;
    unsigned r = v.u + 0x7FFF + ((v.u >> 16) & 1);  // round-to-nearest-even
    return (unsigned short)(r >> 16);
}
__device__ __forceinline__ float bf2f(unsigned short u) {
    union { unsigned u; float f; } v; v.u = (unsigned)u << 16; return v.f;
}

// ---------------------------------------------------------------------------
// K1: per-block LDS bucket histogram (column-major out) + x->bf16 fused.
// ---------------------------------------------------------------------------
__global__ __launch_bounds__(256) void hist_xconv_kernel(
    const int* __restrict__ dst, const float* __restrict__ x,
    int* __restrict__ bh, unsigned short* __restrict__ xb)
{
    __shared__ int lh[NBUCK];
    const int t = threadIdx.x, blk = blockIdx.x;
    for (int b = t; b < NBUCK; b += 256) lh[b] = 0;
    __syncthreads();
    const int base = blk * CHUNK;
#pragma unroll
    for (int k = 0; k < CHUNK / 256; ++k) {
        int idx = base + k * 256 + t;
        if (idx < E) atomicAdd(&lh[dst[idx] >> 7], 1);
    }
    __syncthreads();
    for (int b = t; b < NBUCK; b += 256) bh[(size_t)b * NBLK + blk] = lh[b];

    // x -> bf16 (grid-stride over 400000 short8 chunks)
    for (int u = blk * 256 + t; u < 400000; u += NBLK * 256) {
        const float4* xp = (const float4*)x + (size_t)u * 2;
        float4 a = xp[0], b = xp[1];
        short8 c;
        c[0] = (short)f2bf(a.x); c[1] = (short)f2bf(a.y);
        c[2] = (short)f2bf(a.z); c[3] = (short)f2bf(a.w);
        c[4] = (short)f2bf(b.x); c[5] = (short)f2bf(b.y);
        c[6] = (short)f2bf(b.z); c[7] = (short)f2bf(b.w);
        ((short8*)xb)[u] = c;
    }
}

// ---------------------------------------------------------------------------
// K2: two-level exclusive scan of bh[SC_N] -> sc[SC_N].
// ---------------------------------------------------------------------------
__global__ __launch_bounds__(256) void scan_bsum_kernel(
    const int* __restrict__ bh, int* __restrict__ bsum)
{
    __shared__ int s[256];
    int t = threadIdx.x;
    int i = blockIdx.x * 256 + t;
    s[t] = (i < SC_N) ? bh[i] : 0;
    __syncthreads();
    for (int off = 128; off > 0; off >>= 1) {
        if (t < off) s[t] += s[t + off];
        __syncthreads();
    }
    if (t == 0) bsum[blockIdx.x] = s[0];
}

__global__ __launch_bounds__(256) void scan_partials_kernel(
    const int* __restrict__ bsum, int* __restrict__ boff)
{
    __shared__ int s[256];
    __shared__ int carry;
    int t = threadIdx.x;
    if (t == 0) carry = 0;
    __syncthreads();
    for (int c = 0; c < SCB; c += 256) {
        int i = c + t;
        int v = (i < SCB) ? bsum[i] : 0;
        s[t] = v;
        __syncthreads();
        for (int off = 1; off < 256; off <<= 1) {
            int u = (t >= off) ? s[t - off] : 0;
            __syncthreads();
            s[t] += u;
            __syncthreads();
        }
        if (i < SCB) boff[i] = carry + s[t] - v;
        __syncthreads();
        if (t == 0) carry += s[255];
        __syncthreads();
    }
}

__global__ __launch_bounds__(256) void scan_write_kernel(
    const int* __restrict__ bh, const int* __restrict__ boff,
    int* __restrict__ sc)
{
    __shared__ int s[256];
    int t = threadIdx.x;
    int i = blockIdx.x * 256 + t;
    int v = (i < SC_N) ? bh[i] : 0;
    s[t] = v;
    __syncthreads();
    for (int off = 1; off < 256; off <<= 1) {
        int u = (t >= off) ? s[t - off] : 0;
        __syncthreads();
        s[t] += u;
        __syncthreads();
    }
    if (i < SC_N) sc[i] = boff[blockIdx.x] + s[t] - v;
}

// ---------------------------------------------------------------------------
// K3: scatter into bucket-partitioned tmp (block-private contiguous runs).
// Payload ((dst&127)<<20 | eid, src).
// ---------------------------------------------------------------------------
__global__ __launch_bounds__(256) void scatter_kernel(
    const int* __restrict__ src, const int* __restrict__ dst,
    const int* __restrict__ sc, int2* __restrict__ tmp)
{
    __shared__ int lcur[NBUCK];
    const int t = threadIdx.x, blk = blockIdx.x;
    for (int b = t; b < NBUCK; b += 256) lcur[b] = sc[(size_t)b * NBLK + blk];
    __syncthreads();
    const int base = blk * CHUNK;
#pragma unroll
    for (int k = 0; k < CHUNK / 256; ++k) {
        int idx = base + k * 256 + t;
        if (idx < E) {
            int d = dst[idx];
            int p = atomicAdd(&lcur[d >> 7], 1);
            tmp[p] = make_int2(((d & 127) << 20) | idx, src[idx]);
        }
    }
}

// ---------------------------------------------------------------------------
// K4: per-bucket sort (512 threads). Emits split ssrc/seid streams + offs.
// ---------------------------------------------------------------------------
__global__ __launch_bounds__(512) void bucket_sort_kernel(
    const int2* __restrict__ tmp, const int* __restrict__ sc,
    int* __restrict__ ssrc, int* __restrict__ seid, int* __restrict__ offs)
{
    __shared__ int2 slds[BCAP];
    __shared__ int scnt[128], ssc[128], scur[128];
    const int b = blockIdx.x, t = threadIdx.x;
    const int start = sc[(size_t)b * NBLK];
    const int end = (b == NBUCK - 1) ? E : sc[(size_t)(b + 1) * NBLK];
    const int cnt = end - start;
    if (t < 128) scnt[t] = 0;
    __syncthreads();

    int2 ec[8];
    int myn = 0;
#pragma unroll
    for (int k = 0; k < 8; ++k) {
        int idx = t + k * 512;
        if (idx < cnt) {
            ec[k] = tmp[start + idx];
            atomicAdd(&scnt[ec[k].x >> 20], 1);
            myn = k + 1;
        }
    }
    __syncthreads();

    int v = (t < 128) ? scnt[t] : 0;
    if (t < 128) ssc[t] = v;
    __syncthreads();
    for (int off = 1; off < 128; off <<= 1) {
        int u = (t >= off && t < 128) ? ssc[t - off] : 0;
        __syncthreads();
        if (t < 128) ssc[t] += u;
        __syncthreads();
    }
    if (t < 128) {
        int ex = ssc[t] - v;           // exclusive scan
        scur[t] = ex;
        int node = b * 128 + t;
        if (node < N) offs[node] = start + ex;
    }
    if (b == NBUCK - 1 && t == 0) offs[N] = E;
    __syncthreads();

#pragma unroll
    for (int k = 0; k < 8; ++k) {
        if (k < myn) {
            int dl = ec[k].x >> 20;
            int p = atomicAdd(&scur[dl], 1);
            slds[p] = make_int2(ec[k].y, ec[k].x & 0xFFFFF);  // (src, eid)
        }
    }
    __syncthreads();
    for (int k = t; k < cnt; k += 512) {
        int2 vv = slds[k];
        ssrc[start + k] = vv.x;
        seid[start + k] = vv.y;
    }
}

// ---------------------------------------------------------------------------
// prep_weights: weights -> bf16 transposed [out][k] + graph offsets.
// ---------------------------------------------------------------------------
__global__ __launch_bounds__(256) void prep_weights_kernel(
    const float* __restrict__ lin1_w, const float* __restrict__ lin2_w,
    const float* __restrict__ fc1_w, const float* __restrict__ fc2_w,
    const int* __restrict__ batch,
    unsigned short* __restrict__ Wl1, unsigned short* __restrict__ Wl2,
    unsigned short* __restrict__ Wt1, unsigned short* __restrict__ Wt2,
    int* __restrict__ gofs)
{
    int id = blockIdx.x * 256 + threadIdx.x;
    if (id < 20480) {                       // 128*160
        int o = id / 160, k = id % 160;
        Wl1[id] = (k < 144) ? f2bf(lin1_w[(size_t)k * 128 + o]) : (unsigned short)0;
    } else if (id < 57344) {                // +128*288
        int id2 = id - 20480;
        int o = id2 / 288, k = id2 % 288;
        Wl2[id2] = (k < 272) ? f2bf(lin2_w[(size_t)k * 128 + o]) : (unsigned short)0;
    } else if (id < 122880) {               // +256*256
        int id2 = id - 57344;
        int k = id2 & 255, o = id2 >> 8;
        Wt1[id2] = f2bf(fc1_w[(size_t)k * 256 + o]);
    } else if (id < 139264) {               // +64*256
        int id2 = id - 122880;
        int k = id2 & 255, o = id2 >> 8;
        Wt2[id2] = f2bf(fc2_w[(size_t)k * 64 + o]);
    } else if (id < 139264 + G + 1) {       // graph offsets
        int g = id - 139264;
        int lo = 0, hi = N;
        while (lo < hi) {
            int mid = (lo + hi) >> 1;
            if (batch[mid] < g) lo = mid + 1; else hi = mid;
        }
        gofs[g] = lo;
    }
}

// ---------------------------------------------------------------------------
// gather1x (XCD-sliced): agg_x[n][16s..16s+16) = sum_e xb[src(e)][slice].
// slice = blockIdx&3 -> XCD x handles only slice x&3 (1.6MB, L2-resident).
// Wave = 4 nodes x 16 feats; edge ids batch-loaded and shfl-broadcast
// within each 16-lane subgroup (shfl src always in the active subgroup).
// ---------------------------------------------------------------------------
__global__ __launch_bounds__(256) void gather1x_kernel(
    const unsigned short* __restrict__ xb, const int* __restrict__ ssrc,
    const int* __restrict__ offs, float* __restrict__ agg_x)
{
    const int t = threadIdx.x;
    const int slice = blockIdx.x & 3;
    const int nb = blockIdx.x >> 2;
    const int w = t >> 6, l = t & 63;
    const int q = l >> 4, f = l & 15;
    const int node = nb * 16 + w * 4 + q;     // N%16==0: no tail
    const int start = offs[node];
    const int cnt = offs[node + 1] - start;
    const unsigned short* xs = xb + slice * 16 + f;
    float a0 = 0, a1 = 0, a2 = 0, a3 = 0;
    for (int cb = 0; cb < cnt; cb += 16) {
        int m = min(cnt - cb, 16);
        int sv = ssrc[start + cb + min(f, m - 1)];
        int j = 0;
        for (; j + 4 <= m; j += 4) {
            int s0 = __shfl(sv, q * 16 + j);
            int s1 = __shfl(sv, q * 16 + j + 1);
            int s2 = __shfl(sv, q * 16 + j + 2);
            int s3 = __shfl(sv, q * 16 + j + 3);
            a0 += bf2f(xs[(size_t)s0 * 64]);
            a1 += bf2f(xs[(size_t)s1 * 64]);
            a2 += bf2f(xs[(size_t)s2 * 64]);
            a3 += bf2f(xs[(size_t)s3 * 64]);
        }
        for (; j < m; ++j) {
            int s0 = __shfl(sv, q * 16 + j);
            a0 += bf2f(xs[(size_t)s0 * 64]);
        }
    }
    agg_x[(size_t)node * 64 + slice * 16 + f] = (a0 + a1) + (a2 + a3);
}

// ---------------------------------------------------------------------------
// gather1ea: agg_eb[n][f] = bf16( sum_e ea[eid(e)][f] ). Wave = 4 nodes x
// 16 feats, all lanes active; each edge's 64B ea row read once.
// ---------------------------------------------------------------------------
__global__ __launch_bounds__(256) void gather1ea_kernel(
    const float* __restrict__ ea, const int* __restrict__ seid,
    const int* __restrict__ offs, unsigned short* __restrict__ agg_eb)
{
    const int t = threadIdx.x;
    const int nb = blockIdx.x;
    const int w = t >> 6, l = t & 63;
    const int q = l >> 4, f = l & 15;
    const int node = nb * 16 + w * 4 + q;
    const int start = offs[node];
    const int cnt = offs[node + 1] - start;
    float a0 = 0, a1 = 0, a2 = 0, a3 = 0;
    for (int cb = 0; cb < cnt; cb += 16) {
        int m = min(cnt - cb, 16);
        int ev = seid[start + cb + min(f, m - 1)];
        int j = 0;
        for (; j + 4 <= m; j += 4) {
            int e0 = __shfl(ev, q * 16 + j);
            int e1 = __shfl(ev, q * 16 + j + 1);
            int e2 = __shfl(ev, q * 16 + j + 2);
            int e3 = __shfl(ev, q * 16 + j + 3);
            a0 += ea[(size_t)e0 * 16 + f];
            a1 += ea[(size_t)e1 * 16 + f];
            a2 += ea[(size_t)e2 * 16 + f];
            a3 += ea[(size_t)e3 * 16 + f];
        }
        for (; j < m; ++j) {
            int e0 = __shfl(ev, q * 16 + j);
            a0 += ea[(size_t)e0 * 16 + f];
        }
    }
    agg_eb[(size_t)node * 16 + f] = f2bf((a0 + a1) + (a2 + a3));
}

// ---------------------------------------------------------------------------
// gather2 (XCD-sliced): agg_h[n][16s..) = sum_e h1[src(e)][slice].
// slice = blockIdx&7 -> each XCD touches a 1.6MB h1 slice (L2-resident).
// ---------------------------------------------------------------------------
__global__ __launch_bounds__(256) void gather2_kernel(
    const unsigned short* __restrict__ h1, const int* __restrict__ ssrc,
    const int* __restrict__ offs, float* __restrict__ agg_h)
{
    const int t = threadIdx.x;
    const int slice = blockIdx.x & 7;
    const int nb = blockIdx.x >> 3;
    const int w = t >> 6, l = t & 63;
    const int q = l >> 4, f = l & 15;
    const int node = nb * 16 + w * 4 + q;
    const int start = offs[node];
    const int cnt = offs[node + 1] - start;
    const unsigned short* hs = h1 + slice * 16 + f;
    float a0 = 0, a1 = 0, a2 = 0, a3 = 0;
    for (int cb = 0; cb < cnt; cb += 16) {
        int m = min(cnt - cb, 16);
        int sv = ssrc[start + cb + min(f, m - 1)];
        int j = 0;
        for (; j + 4 <= m; j += 4) {
            int s0 = __shfl(sv, q * 16 + j);
            int s1 = __shfl(sv, q * 16 + j + 1);
            int s2 = __shfl(sv, q * 16 + j + 2);
            int s3 = __shfl(sv, q * 16 + j + 3);
            a0 += bf2f(hs[(size_t)s0 * 128]);
            a1 += bf2f(hs[(size_t)s1 * 128]);
            a2 += bf2f(hs[(size_t)s2 * 128]);
            a3 += bf2f(hs[(size_t)s3 * 128]);
        }
        for (; j < m; ++j) {
            int s0 = __shfl(sv, q * 16 + j);
            a0 += bf2f(hs[(size_t)s0 * 128]);
        }
    }
    agg_h[(size_t)node * 128 + slice * 16 + f] = (a0 + a1) + (a2 + a3);
}

// ---------------------------------------------------------------------------
// combine1 (MFMA, 64 nodes/block, 8 waves): h1 = relu(bn1(relu(A1@W1+dt*b1)))
// A1 row = [ dt*x | agg_x + x | agg_e + 1 | 0-pad ], K=160, rows 320B swz'd.
// ---------------------------------------------------------------------------
__global__ __launch_bounds__(512) void combine1_kernel(
    const unsigned short* __restrict__ xb, const int* __restrict__ offs,
    const unsigned short* __restrict__ agg_eb, const float* __restrict__ agg_x,
    const unsigned short* __restrict__ Wl1, const float* __restrict__ bias,
    const float* __restrict__ bng, const float* __restrict__ bnb,
    unsigned short* __restrict__ h1)
{
    __shared__ unsigned short sA[64 * 160];  // 20KB, rows of 320B
    __shared__ float sdeg[64];
    const int t = threadIdx.x;
    const int base = blockIdx.x * 64;
    {
        int n = t >> 3, kk = t & 7;
        int i = min(base + n, N - 1);
        float dt = (float)(offs[i + 1] - offs[i]) + 1.0f;   // +1 self loop
        const unsigned short* xr = xb + (size_t)i * 64;
        const float* axr = agg_x + (size_t)i * 64;
        char* sp = (char*)sA;
        int rb = n * 320, swz = (n & 7) << 4;
#pragma unroll
        for (int j = 0; j < 8; ++j) {
            int c = kk + j * 8;
            float xv = bf2f(xr[c]);
            *(unsigned short*)(sp + ((rb + c * 2) ^ swz)) = f2bf(dt * xv);
            *(unsigned short*)(sp + ((rb + (c + 64) * 2) ^ swz)) = f2bf(axr[c] + xv);
        }
        *(unsigned short*)(sp + ((rb + (128 + kk) * 2) ^ swz)) =
            f2bf(bf2f(agg_eb[(size_t)i * 16 + kk]) + 1.0f);
        *(unsigned short*)(sp + ((rb + (136 + kk) * 2) ^ swz)) =
            f2bf(bf2f(agg_eb[(size_t)i * 16 + 8 + kk]) + 1.0f);
        *(unsigned short*)(sp + ((rb + (144 + kk) * 2) ^ swz)) = 0;
        *(unsigned short*)(sp + ((rb + (152 + kk) * 2) ^ swz)) = 0;
        if (kk == 0) sdeg[n] = dt;
    }
    __syncthreads();

    const int w = t >> 6, l = t & 63, lr = l & 15, lg = l >> 4;
    const int outc = w * 16 + lr;
    short8 bf[5];
    {
        const unsigned short* wp = Wl1 + (size_t)outc * 160 + lg * 8;
#pragma unroll
        for (int s = 0; s < 5; ++s) bf[s] = *(const short8*)(wp + s * 32);
    }
    const float bo = bias[outc];
    const float sc = bng[outc] * 0.99999500003749974f;  // 1/sqrt(1+1e-5)
    const float bb = bnb[outc];
#pragma unroll
    for (int ng = 0; ng < 4; ++ng) {
        int row = ng * 16 + lr, sw = (row & 7) << 4;
        short8 af[5];
#pragma unroll
        for (int s = 0; s < 5; ++s)
            af[s] = *(const short8*)((const char*)sA + ((row * 320 + s * 64 + lg * 16) ^ sw));
        f32x4 acc = {0.0f, 0.0f, 0.0f, 0.0f};
#pragma unroll
        for (int s = 0; s < 5; ++s)
            acc = __builtin_amdgcn_mfma_f32_16x16x32_bf16(af[s], bf[s], acc, 0, 0, 0);
#pragma unroll
        for (int r = 0; r < 4; ++r) {
            int node = ng * 16 + lg * 4 + r;
            float v = fmaxf(acc[r] + sdeg[node] * bo, 0.0f);
            v = fmaxf(v * sc + bb, 0.0f);
            if (base + node < N)
                h1[(size_t)(base + node) * 128 + outc] = f2bf(v);
        }
    }
}

// ---------------------------------------------------------------------------
// combine2 (MFMA, 64 nodes/block, 8 waves): same template, K=288, rows 576B.
// ---------------------------------------------------------------------------
__global__ __launch_bounds__(512) void combine2_kernel(
    const unsigned short* __restrict__ h1, const int* __restrict__ offs,
    const unsigned short* __restrict__ agg_eb, const float* __restrict__ agg_h,
    const unsigned short* __restrict__ Wl2, const float* __restrict__ bias,
    const float* __restrict__ bng, const float* __restrict__ bnb,
    unsigned short* __restrict__ h2)
{
    __shared__ unsigned short sA[64 * 288];  // 36KB, rows of 576B
    __shared__ float sdeg[64];
    const int t = threadIdx.x;
    const int base = blockIdx.x * 64;
    {
        int n = t >> 3, kk = t & 7;
        int i = min(base + n, N - 1);
        float dt = (float)(offs[i + 1] - offs[i]) + 1.0f;
        const unsigned short* hr = h1 + (size_t)i * 128;
        const float* ahr = agg_h + (size_t)i * 128;
        char* sp = (char*)sA;
        int rb = n * 576, swz = (n & 7) << 4;
#pragma unroll
        for (int j = 0; j < 16; ++j) {
            int c = kk + j * 8;
            float hv = bf2f(hr[c]);
            *(unsigned short*)(sp + ((rb + c * 2) ^ swz)) = f2bf(dt * hv);
            *(unsigned short*)(sp + ((rb + (c + 128) * 2) ^ swz)) = f2bf(ahr[c] + hv);
        }
        *(unsigned short*)(sp + ((rb + (256 + kk) * 2) ^ swz)) =
            f2bf(bf2f(agg_eb[(size_t)i * 16 + kk]) + 1.0f);
        *(unsigned short*)(sp + ((rb + (264 + kk) * 2) ^ swz)) =
            f2bf(bf2f(agg_eb[(size_t)i * 16 + 8 + kk]) + 1.0f);
        *(unsigned short*)(sp + ((rb + (272 + kk) * 2) ^ swz)) = 0;
        *(unsigned short*)(sp + ((rb + (280 + kk) * 2) ^ swz)) = 0;
        if (kk == 0) sdeg[n] = dt;
    }
    __syncthreads();

    const int w = t >> 6, l = t & 63, lr = l & 15, lg = l >> 4;
    const int outc = w * 16 + lr;
    short8 bf[9];
    {
        const unsigned short* wp = Wl2 + (size_t)outc * 288 + lg * 8;
#pragma unroll
        for (int s = 0; s < 9; ++s) bf[s] = *(const short8*)(wp + s * 32);
    }
    const float bo = bias[outc];
    const float sc = bng[outc] * 0.99999500003749974f;
    const float bb = bnb[outc];
#pragma unroll
    for (int ng = 0; ng < 4; ++ng) {
        int row = ng * 16 + lr, sw = (row & 7) << 4;
        short8 af[9];
#pragma unroll
        for (int s = 0; s < 9; ++s)
            af[s] = *(const short8*)((const char*)sA + ((row * 576 + s * 64 + lg * 16) ^ sw));
        f32x4 acc = {0.0f, 0.0f, 0.0f, 0.0f};
#pragma unroll
        for (int s = 0; s < 9; ++s)
            acc = __builtin_amdgcn_mfma_f32_16x16x32_bf16(af[s], bf[s], acc, 0, 0, 0);
#pragma unroll
        for (int r = 0; r < 4; ++r) {
            int node = ng * 16 + lg * 4 + r;
            float v = fmaxf(acc[r] + sdeg[node] * bo, 0.0f);
            v = fmaxf(v * sc + bb, 0.0f);
            if (base + node < N)
                h2[(size_t)(base + node) * 128 + outc] = f2bf(v);
        }
    }
}

// ---------------------------------------------------------------------------
// ge: deterministic global_add_pool. One block per graph (batch sorted).
// ---------------------------------------------------------------------------
__global__ __launch_bounds__(256) void ge_kernel(
    const unsigned short* __restrict__ h2, const int* __restrict__ gofs,
    float* __restrict__ ge)
{
    __shared__ float s[256];
    int g = blockIdx.x, t = threadIdx.x;
    int lo = gofs[g], hi = gofs[g + 1];
    int col = t & 127, half = t >> 7;
    float acc = 0.0f;
    for (int r = lo + half; r < hi; r += 2)
        acc += bf2f(h2[(size_t)r * 128 + col]);
    s[t] = acc;
    __syncthreads();
    if (t < 128) ge[(size_t)g * 128 + t] = s[t] + s[t + 128];
}

// ---------------------------------------------------------------------------
// final_mfma (64 nodes/block, 8 waves):
//   out = relu([h2 | ge[batch]]_bf16 @ Wt1^T + b1) @ Wt2^T + b2
// ---------------------------------------------------------------------------
__global__ __launch_bounds__(512) void final_mfma_kernel(
    const unsigned short* __restrict__ h2, const float* __restrict__ ge,
    const int* __restrict__ batch,
    const unsigned short* __restrict__ Wt1, const float* __restrict__ b1,
    const unsigned short* __restrict__ Wt2, const float* __restrict__ b2,
    float* __restrict__ out)
{
    __shared__ unsigned short sA[64 * 256];  // 32KB node_in, 512B rows swz'd
    __shared__ unsigned short sH[64 * 256];  // 32KB hidden
    const int t = threadIdx.x;
    const int base = blockIdx.x * 64;

    {   // stage node_in = [h2 | ge[batch]] as bf16, 8 threads/row
        int n = t >> 3, idx = t & 7;
        int i = min(base + n, N - 1);
        int rb = n * 512, swz = (n & 7) << 4;
        if (idx < 4) {
            const short8* hp = (const short8*)(h2 + (size_t)i * 128 + idx * 32);
#pragma unroll
            for (int q = 0; q < 4; ++q)
                *(short8*)((char*)sA + ((rb + idx * 64 + q * 16) ^ swz)) = hp[q];
        } else {
            const float4* gp = (const float4*)(ge + (size_t)batch[i] * 128 + (idx - 4) * 32);
#pragma unroll
            for (int q = 0; q < 4; ++q) {
                float4 a = gp[2 * q], b = gp[2 * q + 1];
                short8 c;
                c[0] = (short)f2bf(a.x); c[1] = (short)f2bf(a.y);
                c[2] = (short)f2bf(a.z); c[3] = (short)f2bf(a.w);
                c[4] = (short)f2bf(b.x); c[5] = (short)f2bf(b.y);
                c[6] = (short)f2bf(b.z); c[7] = (short)f2bf(b.w);
                *(short8*)((char*)sA + ((rb + 256 + (idx - 4) * 64 + q * 16) ^ swz)) = c;
            }
        }
    }
    __syncthreads();

    const int w = t >> 6, l = t & 63, lr = l & 15, lg = l >> 4;

    // ---- fc1 ----
#pragma unroll
    for (int tt = 0; tt < 2; ++tt) {
        int outc = (2 * w + tt) * 16 + lr;
        short8 bf[8];
        {
            const unsigned short* wp = Wt1 + (size_t)outc * 256 + lg * 8;
#pragma unroll
            for (int s = 0; s < 8; ++s) bf[s] = *(const short8*)(wp + s * 32);
        }
        float bb = b1[outc];
#pragma unroll
        for (int ng = 0; ng < 4; ++ng) {
            int row = ng * 16 + lr, sw = (row & 7) << 4;
            short8 af[8];
#pragma unroll
            for (int s = 0; s < 8; ++s)
                af[s] = *(const short8*)((const char*)sA + ((row * 512 + s * 64 + lg * 16) ^ sw));
            f32x4 acc = {0.0f, 0.0f, 0.0f, 0.0f};
#pragma unroll
            for (int s = 0; s < 8; ++s)
                acc = __builtin_amdgcn_mfma_f32_16x16x32_bf16(af[s], bf[s], acc, 0, 0, 0);
#pragma unroll
            for (int r = 0; r < 4; ++r) {
                int node = ng * 16 + lg * 4 + r;
                float hv = fmaxf(acc[r] + bb, 0.0f);
                int byte = (node * 512 + outc * 2) ^ ((node & 7) << 4);
                *(unsigned short*)((char*)sH + byte) = f2bf(hv);
            }
        }
    }
    __syncthreads();

    // ---- fc2 ----
    {
        int ct = w & 3, ngbase = (w >> 2) * 2;
        int outc = ct * 16 + lr;
        short8 bf[8];
        {
            const unsigned short* wp = Wt2 + (size_t)outc * 256 + lg * 8;
#pragma unroll
            for (int s = 0; s < 8; ++s) bf[s] = *(const short8*)(wp + s * 32);
        }
        float bb = b2[outc];
#pragma unroll
        for (int k = 0; k < 2; ++k) {
            int row = (ngbase + k) * 16 + lr, sw = (row & 7) << 4;
            short8 ah[8];
#pragma unroll
            for (int s = 0; s < 8; ++s)
                ah[s] = *(const short8*)((const char*)sH + ((row * 512 + s * 64 + lg * 16) ^ sw));
            f32x4 acc = {0.0f, 0.0f, 0.0f, 0.0f};
#pragma unroll
            for (int s = 0; s < 8; ++s)
                acc = __builtin_amdgcn_mfma_f32_16x16x32_bf16(ah[s], bf[s], acc, 0, 0, 0);
#pragma unroll
            for (int r = 0; r < 4; ++r) {
                int node = (ngbase + k) * 16 + lg * 4 + r;
                if (base + node < N)
                    out[(size_t)(base + node) * 64 + outc] = acc[r] + bb;
            }
        }
    }
}

// ---------------------------------------------------------------------------
extern "C" void kernel_launch(void* const* d_in, const int* in_sizes, int n_in,
                              void* d_out, int out_size, void* d_ws, size_t ws_size,
                              hipStream_t stream)
{
    const float* x      = (const float*)d_in[0];
    const int*   src    = (const int*)d_in[1];
    const int*   dst    = (const int*)d_in[2];
    const float* eattr  = (const float*)d_in[3];
    const int*   batch  = (const int*)d_in[4];
    const float* lin1_w = (const float*)d_in[5];
    const float* lin1_b = (const float*)d_in[6];
    const float* lin2_w = (const float*)d_in[7];
    const float* lin2_b = (const float*)d_in[8];
    const float* bn1_g  = (const float*)d_in[9];
    const float* bn1_b  = (const float*)d_in[10];
    const float* bn2_g  = (const float*)d_in[11];
    const float* bn2_b  = (const float*)d_in[12];
    const float* fc1_w  = (const float*)d_in[13];
    const float* fc1_b  = (const float*)d_in[14];
    const float* fc2_w  = (const float*)d_in[15];
    const float* fc2_b  = (const float*)d_in[16];
    float* out = (float*)d_out;

    // Workspace (~62.3 MB), no zeroing needed (every buffer fully written):
    //   bh | sc | bsum | boff | ge | gofs | offs | ssrc | seid | agg_eb |
    //   aggreg (tmp int2 [0,6.4MB) during CSR build; agg_x f32 [0,12.8MB);
    //           xb bf16 at [12.8,19.2MB); agg_h full 25.6MB)
    //   | h1 bf16 | h2 bf16 | Wl1 | Wl2 | Wt1 | Wt2
    char* p = (char*)d_ws;
    auto alloc = [&](size_t bytes) {
        char* r = p;
        p += (bytes + 15) & ~(size_t)15;
        return r;
    };
    int*   bh     = (int*)alloc((size_t)4 * SC_N);
    int*   sc     = (int*)alloc((size_t)4 * SC_N);
    int*   bsum   = (int*)alloc((size_t)4 * SCB);
    int*   boff   = (int*)alloc((size_t)4 * SCB);
    float* ge     = (float*)alloc((size_t)512 * G);
    int*   gofs   = (int*)alloc((size_t)4 * (G + 1));
    int*   offs   = (int*)alloc((size_t)4 * (N + 1));
    int*   ssrc   = (int*)alloc((size_t)4 * E);
    int*   seid   = (int*)alloc((size_t)4 * E);
    unsigned short* agg_eb = (unsigned short*)alloc((size_t)32 * N);
    float* aggreg = (float*)alloc((size_t)512 * N);   // 128N fp32
    int2*  tmp    = (int2*)aggreg;                    // [0, 8E) bytes, CSR phase
    float* agg_x  = aggreg;                           // 64N f32
    unsigned short* xb = (unsigned short*)((char*)aggreg + (size_t)256 * N);
    float* agg_h  = aggreg;                           // 128N f32
    unsigned short* h1  = (unsigned short*)alloc((size_t)256 * N);
    unsigned short* h2  = (unsigned short*)alloc((size_t)256 * N);
    unsigned short* Wl1 = (unsigned short*)alloc(2 * 20480);
    unsigned short* Wl2 = (unsigned short*)alloc(2 * 36864);
    unsigned short* Wt1 = (unsigned short*)alloc(2 * 65536);
    unsigned short* Wt2 = (unsigned short*)alloc(2 * 16384);

    // --- CSR build: block-local 3-phase counting sort + weight prep ---
    hist_xconv_kernel<<<NBLK, 256, 0, stream>>>(dst, x, bh, xb);
    scan_bsum_kernel<<<SCB, 256, 0, stream>>>(bh, bsum);
    scan_partials_kernel<<<1, 256, 0, stream>>>(bsum, boff);
    scan_write_kernel<<<SCB, 256, 0, stream>>>(bh, boff, sc);
    scatter_kernel<<<NBLK, 256, 0, stream>>>(src, dst, sc, tmp);
    bucket_sort_kernel<<<NBUCK, 512, 0, stream>>>(tmp, sc, ssrc, seid, offs);
    prep_weights_kernel<<<549, 256, 0, stream>>>(lin1_w, lin2_w, fc1_w, fc2_w,
                                                 batch, Wl1, Wl2, Wt1, Wt2, gofs);

    const int NB64 = (N + 63) / 64;   // 782
    const int NB16 = N / 16;          // 3125 (N%16==0)

    // --- Layer 1 ---
    gather1x_kernel<<<4 * NB16, 256, 0, stream>>>(xb, ssrc, offs, agg_x);
    gather1ea_kernel<<<NB16, 256, 0, stream>>>(eattr, seid, offs, agg_eb);
    combine1_kernel<<<NB64, 512, 0, stream>>>(xb, offs, agg_eb, agg_x,
                                              Wl1, lin1_b, bn1_g, bn1_b, h1);

    // --- Layer 2 ---
    gather2_kernel<<<8 * NB16, 256, 0, stream>>>(h1, ssrc, offs, agg_h);
    combine2_kernel<<<NB64, 512, 0, stream>>>(h1, offs, agg_eb, agg_h,
                                              Wl2, lin2_b, bn2_g, bn2_b, h2);

    // --- Pool + readout ---
    ge_kernel<<<G, 256, 0, stream>>>(h2, gofs, ge);
    final_mfma_kernel<<<NB64, 512, 0, stream>>>(h2, ge, batch,
                                                Wt1, fc1_b, Wt2, fc2_b, out);
}

// Round 11
// 194.831 us; speedup vs baseline: 1.3516x; 1.3516x over previous
//
#include <hip/hip_runtime.h>

// Problem constants (fixed by the reference)
constexpr int N = 50000;
constexpr int E = 800000;
constexpr int G = 1024;

constexpr int NBUCK = (N + 127) / 128;     // 391 buckets of 128 nodes
constexpr int CHUNK = 4096;                // edges per pass-1 block
constexpr int NBLK  = (E + CHUNK - 1) / CHUNK;  // 196
constexpr int SC_N  = NBUCK * NBLK;        // 76636 histogram entries
constexpr int SCB   = (SC_N + 255) / 256;  // 300 scan blocks
constexpr int BCAP  = 4096;                // bucket capacity (mean 2046, +45 sigma)

typedef __attribute__((ext_vector_type(8))) short short8;
typedef __attribute__((ext_vector_type(4))) float f32x4;

__device__ __forceinline__ unsigned short f2bf(float x) {
    union { float f; unsigned u; } v; v.f = x;
    unsigned r = v.u + 0x7FFF + ((v.u >> 16) & 1);  // round-to-nearest-even
    return (unsigned short)(r >> 16);
}
__device__ __forceinline__ float bf2f(unsigned short u) {
    union { unsigned u; float f; } v; v.u = (unsigned)u << 16; return v.f;
}

// ---------------------------------------------------------------------------
// K1: per-block LDS bucket histogram (column-major out) + x->bf16 fused.
// ---------------------------------------------------------------------------
__global__ __launch_bounds__(256) void hist_xconv_kernel(
    const int* __restrict__ dst, const float* __restrict__ x,
    int* __restrict__ bh, unsigned short* __restrict__ xb)
{
    __shared__ int lh[NBUCK];
    const int t = threadIdx.x, blk = blockIdx.x;
    for (int b = t; b < NBUCK; b += 256) lh[b] = 0;
    __syncthreads();
    const int base = blk * CHUNK;
#pragma unroll
    for (int k = 0; k < CHUNK / 256; ++k) {
        int idx = base + k * 256 + t;
        if (idx < E) atomicAdd(&lh[dst[idx] >> 7], 1);
    }
    __syncthreads();
    for (int b = t; b < NBUCK; b += 256) bh[(size_t)b * NBLK + blk] = lh[b];

    // x -> bf16 (grid-stride over 400000 short8 chunks)
    for (int u = blk * 256 + t; u < 400000; u += NBLK * 256) {
        const float4* xp = (const float4*)x + (size_t)u * 2;
        float4 a = xp[0], b = xp[1];
        short8 c;
        c[0] = (short)f2bf(a.x); c[1] = (short)f2bf(a.y);
        c[2] = (short)f2bf(a.z); c[3] = (short)f2bf(a.w);
        c[4] = (short)f2bf(b.x); c[5] = (short)f2bf(b.y);
        c[6] = (short)f2bf(b.z); c[7] = (short)f2bf(b.w);
        ((short8*)xb)[u] = c;
    }
}

// ---------------------------------------------------------------------------
// K2: two-level exclusive scan of bh[SC_N] -> sc[SC_N].
// ---------------------------------------------------------------------------
__global__ __launch_bounds__(256) void scan_bsum_kernel(
    const int* __restrict__ bh, int* __restrict__ bsum)
{
    __shared__ int s[256];
    int t = threadIdx.x;
    int i = blockIdx.x * 256 + t;
    s[t] = (i < SC_N) ? bh[i] : 0;
    __syncthreads();
    for (int off = 128; off > 0; off >>= 1) {
        if (t < off) s[t] += s[t + off];
        __syncthreads();
    }
    if (t == 0) bsum[blockIdx.x] = s[0];
}

__global__ __launch_bounds__(256) void scan_partials_kernel(
    const int* __restrict__ bsum, int* __restrict__ boff)
{
    __shared__ int s[256];
    __shared__ int carry;
    int t = threadIdx.x;
    if (t == 0) carry = 0;
    __syncthreads();
    for (int c = 0; c < SCB; c += 256) {
        int i = c + t;
        int v = (i < SCB) ? bsum[i] : 0;
        s[t] = v;
        __syncthreads();
        for (int off = 1; off < 256; off <<= 1) {
            int u = (t >= off) ? s[t - off] : 0;
            __syncthreads();
            s[t] += u;
            __syncthreads();
        }
        if (i < SCB) boff[i] = carry + s[t] - v;
        __syncthreads();
        if (t == 0) carry += s[255];
        __syncthreads();
    }
}

__global__ __launch_bounds__(256) void scan_write_kernel(
    const int* __restrict__ bh, const int* __restrict__ boff,
    int* __restrict__ sc)
{
    __shared__ int s[256];
    int t = threadIdx.x;
    int i = blockIdx.x * 256 + t;
    int v = (i < SC_N) ? bh[i] : 0;
    s[t] = v;
    __syncthreads();
    for (int off = 1; off < 256; off <<= 1) {
        int u = (t >= off) ? s[t - off] : 0;
        __syncthreads();
        s[t] += u;
        __syncthreads();
    }
    if (i < SC_N) sc[i] = boff[blockIdx.x] + s[t] - v;
}

// ---------------------------------------------------------------------------
// K3: scatter into bucket-partitioned tmp (block-private contiguous runs).
// Payload ((dst&127)<<20 | eid, src).
// ---------------------------------------------------------------------------
__global__ __launch_bounds__(256) void scatter_kernel(
    const int* __restrict__ src, const int* __restrict__ dst,
    const int* __restrict__ sc, int2* __restrict__ tmp)
{
    __shared__ int lcur[NBUCK];
    const int t = threadIdx.x, blk = blockIdx.x;
    for (int b = t; b < NBUCK; b += 256) lcur[b] = sc[(size_t)b * NBLK + blk];
    __syncthreads();
    const int base = blk * CHUNK;
#pragma unroll
    for (int k = 0; k < CHUNK / 256; ++k) {
        int idx = base + k * 256 + t;
        if (idx < E) {
            int d = dst[idx];
            int p = atomicAdd(&lcur[d >> 7], 1);
            tmp[p] = make_int2(((d & 127) << 20) | idx, src[idx]);
        }
    }
}

// ---------------------------------------------------------------------------
// K4: per-bucket sort (512 threads). Emits split ssrc/seid streams + offs.
// ---------------------------------------------------------------------------
__global__ __launch_bounds__(512) void bucket_sort_kernel(
    const int2* __restrict__ tmp, const int* __restrict__ sc,
    int* __restrict__ ssrc, int* __restrict__ seid, int* __restrict__ offs)
{
    __shared__ int2 slds[BCAP];
    __shared__ int scnt[128], ssc[128], scur[128];
    const int b = blockIdx.x, t = threadIdx.x;
    const int start = sc[(size_t)b * NBLK];
    const int end = (b == NBUCK - 1) ? E : sc[(size_t)(b + 1) * NBLK];
    const int cnt = end - start;
    if (t < 128) scnt[t] = 0;
    __syncthreads();

    int2 ec[8];
    int myn = 0;
#pragma unroll
    for (int k = 0; k < 8; ++k) {
        int idx = t + k * 512;
        if (idx < cnt) {
            ec[k] = tmp[start + idx];
            atomicAdd(&scnt[ec[k].x >> 20], 1);
            myn = k + 1;
        }
    }
    __syncthreads();

    int v = (t < 128) ? scnt[t] : 0;
    if (t < 128) ssc[t] = v;
    __syncthreads();
    for (int off = 1; off < 128; off <<= 1) {
        int u = (t >= off && t < 128) ? ssc[t - off] : 0;
        __syncthreads();
        if (t < 128) ssc[t] += u;
        __syncthreads();
    }
    if (t < 128) {
        int ex = ssc[t] - v;           // exclusive scan
        scur[t] = ex;
        int node = b * 128 + t;
        if (node < N) offs[node] = start + ex;
    }
    if (b == NBUCK - 1 && t == 0) offs[N] = E;
    __syncthreads();

#pragma unroll
    for (int k = 0; k < 8; ++k) {
        if (k < myn) {
            int dl = ec[k].x >> 20;
            int p = atomicAdd(&scur[dl], 1);
            slds[p] = make_int2(ec[k].y, ec[k].x & 0xFFFFF);  // (src, eid)
        }
    }
    __syncthreads();
    for (int k = t; k < cnt; k += 512) {
        int2 vv = slds[k];
        ssrc[start + k] = vv.x;
        seid[start + k] = vv.y;
    }
}

// ---------------------------------------------------------------------------
// prep_weights: weights -> bf16 transposed [out][k] + graph offsets.
// ---------------------------------------------------------------------------
__global__ __launch_bounds__(256) void prep_weights_kernel(
    const float* __restrict__ lin1_w, const float* __restrict__ lin2_w,
    const float* __restrict__ fc1_w, const float* __restrict__ fc2_w,
    const int* __restrict__ batch,
    unsigned short* __restrict__ Wl1, unsigned short* __restrict__ Wl2,
    unsigned short* __restrict__ Wt1, unsigned short* __restrict__ Wt2,
    int* __restrict__ gofs)
{
    int id = blockIdx.x * 256 + threadIdx.x;
    if (id < 20480) {                       // 128*160
        int o = id / 160, k = id % 160;
        Wl1[id] = (k < 144) ? f2bf(lin1_w[(size_t)k * 128 + o]) : (unsigned short)0;
    } else if (id < 57344) {                // +128*288
        int id2 = id - 20480;
        int o = id2 / 288, k = id2 % 288;
        Wl2[id2] = (k < 272) ? f2bf(lin2_w[(size_t)k * 128 + o]) : (unsigned short)0;
    } else if (id < 122880) {               // +256*256
        int id2 = id - 57344;
        int k = id2 & 255, o = id2 >> 8;
        Wt1[id2] = f2bf(fc1_w[(size_t)k * 256 + o]);
    } else if (id < 139264) {               // +64*256
        int id2 = id - 122880;
        int k = id2 & 255, o = id2 >> 8;
        Wt2[id2] = f2bf(fc2_w[(size_t)k * 64 + o]);
    } else if (id < 139264 + G + 1) {       // graph offsets
        int g = id - 139264;
        int lo = 0, hi = N;
        while (lo < hi) {
            int mid = (lo + hi) >> 1;
            if (batch[mid] < g) lo = mid + 1; else hi = mid;
        }
        gofs[g] = lo;
    }
}

// ---------------------------------------------------------------------------
// gather1 (round-9 proven structure): agg_xb[i] = bf16(sum xb[src]) (64f),
// agg_eb[i] = bf16(sum ea[eid]) (16f). One wave/node, shfl-broadcast ids.
// ---------------------------------------------------------------------------
__global__ __launch_bounds__(256) void gather1_kernel(
    const unsigned short* __restrict__ xb, const float* __restrict__ ea,
    const int* __restrict__ ssrc, const int* __restrict__ seid,
    const int* __restrict__ offs,
    unsigned short* __restrict__ agg_xb, unsigned short* __restrict__ agg_eb)
{
    int node = blockIdx.x * 4 + (threadIdx.x >> 6);
    int l = threadIdx.x & 63;
    if (node >= N) return;
    int start = offs[node];
    int cnt = offs[node + 1] - start;
    float ax0 = 0, ax1 = 0, ax2 = 0, ax3 = 0;
    float ae0 = 0, ae1 = 0, ae2 = 0, ae3 = 0;
    for (int cb = 0; cb < cnt; cb += 64) {
        int m = min(cnt - cb, 64);
        int slx = ssrc[start + cb + min(l, m - 1)];
        int sly = seid[start + cb + min(l, m - 1)];
        int j = 0;
        for (; j + 4 <= m; j += 4) {
            int s0 = __shfl(slx, j),     e0 = __shfl(sly, j);
            int s1 = __shfl(slx, j + 1), e1 = __shfl(sly, j + 1);
            int s2 = __shfl(slx, j + 2), e2 = __shfl(sly, j + 2);
            int s3 = __shfl(slx, j + 3), e3 = __shfl(sly, j + 3);
            ax0 += bf2f(xb[(size_t)s0 * 64 + l]);
            ax1 += bf2f(xb[(size_t)s1 * 64 + l]);
            ax2 += bf2f(xb[(size_t)s2 * 64 + l]);
            ax3 += bf2f(xb[(size_t)s3 * 64 + l]);
            if (l < 16) {
                ae0 += ea[(size_t)e0 * 16 + l];
                ae1 += ea[(size_t)e1 * 16 + l];
                ae2 += ea[(size_t)e2 * 16 + l];
                ae3 += ea[(size_t)e3 * 16 + l];
            }
        }
        for (; j < m; ++j) {
            int s0 = __shfl(slx, j), e0 = __shfl(sly, j);
            ax0 += bf2f(xb[(size_t)s0 * 64 + l]);
            if (l < 16) ae0 += ea[(size_t)e0 * 16 + l];
        }
    }
    agg_xb[(size_t)node * 64 + l] = f2bf((ax0 + ax1) + (ax2 + ax3));
    if (l < 16) agg_eb[(size_t)node * 16 + l] = f2bf((ae0 + ae1) + (ae2 + ae3));
}

// ---------------------------------------------------------------------------
// gather2 (round-9 proven structure): agg_hb[i] = bf16(sum h1[src]) (128f).
// One wave/node, 2 feats/lane (uint = 2 bf16), packed bf16x2 output.
// ---------------------------------------------------------------------------
__global__ __launch_bounds__(256) void gather2_kernel(
    const unsigned short* __restrict__ h1, const int* __restrict__ ssrc,
    const int* __restrict__ offs, unsigned* __restrict__ agg_hb)
{
    int node = blockIdx.x * 4 + (threadIdx.x >> 6);
    int l = threadIdx.x & 63;
    if (node >= N) return;
    int start = offs[node];
    int cnt = offs[node + 1] - start;
    const unsigned* h = (const unsigned*)h1;  // 64 uints (=128 bf16) per row
    float a0 = 0, b0 = 0, a1 = 0, b1 = 0, a2 = 0, b2 = 0, a3 = 0, b3 = 0;
    for (int cb = 0; cb < cnt; cb += 64) {
        int m = min(cnt - cb, 64);
        int slx = ssrc[start + cb + min(l, m - 1)];
        int j = 0;
        for (; j + 4 <= m; j += 4) {
            int s0 = __shfl(slx, j),     s1 = __shfl(slx, j + 1);
            int s2 = __shfl(slx, j + 2), s3 = __shfl(slx, j + 3);
            unsigned v0 = h[(size_t)s0 * 64 + l];
            unsigned v1 = h[(size_t)s1 * 64 + l];
            unsigned v2 = h[(size_t)s2 * 64 + l];
            unsigned v3 = h[(size_t)s3 * 64 + l];
            a0 += bf2f((unsigned short)(v0 & 0xFFFF)); b0 += bf2f((unsigned short)(v0 >> 16));
            a1 += bf2f((unsigned short)(v1 & 0xFFFF)); b1 += bf2f((unsigned short)(v1 >> 16));
            a2 += bf2f((unsigned short)(v2 & 0xFFFF)); b2 += bf2f((unsigned short)(v2 >> 16));
            a3 += bf2f((unsigned short)(v3 & 0xFFFF)); b3 += bf2f((unsigned short)(v3 >> 16));
        }
        for (; j < m; ++j) {
            int s0 = __shfl(slx, j);
            unsigned v0 = h[(size_t)s0 * 64 + l];
            a0 += bf2f((unsigned short)(v0 & 0xFFFF)); b0 += bf2f((unsigned short)(v0 >> 16));
        }
    }
    unsigned lo = f2bf((a0 + a1) + (a2 + a3));
    unsigned hi = f2bf((b0 + b1) + (b2 + b3));
    agg_hb[(size_t)node * 64 + l] = (hi << 16) | lo;
}

// ---------------------------------------------------------------------------
// combine1 (MFMA, 64 nodes/block, 8 waves): h1 = relu(bn1(relu(A1@W1+dt*b1)))
// A1 row = [ dt*x | agg_x + x | agg_e + 1 | 0-pad ], K=160, rows 320B swz'd.
// ---------------------------------------------------------------------------
__global__ __launch_bounds__(512) void combine1_kernel(
    const unsigned short* __restrict__ xb, const int* __restrict__ offs,
    const unsigned short* __restrict__ agg_eb, const unsigned short* __restrict__ agg_xb,
    const unsigned short* __restrict__ Wl1, const float* __restrict__ bias,
    const float* __restrict__ bng, const float* __restrict__ bnb,
    unsigned short* __restrict__ h1)
{
    __shared__ unsigned short sA[64 * 160];  // 20KB, rows of 320B
    __shared__ float sdeg[64];
    const int t = threadIdx.x;
    const int base = blockIdx.x * 64;
    {
        int n = t >> 3, kk = t & 7;
        int i = min(base + n, N - 1);
        float dt = (float)(offs[i + 1] - offs[i]) + 1.0f;   // +1 self loop
        const unsigned short* xr = xb + (size_t)i * 64;
        const unsigned short* axr = agg_xb + (size_t)i * 64;
        char* sp = (char*)sA;
        int rb = n * 320, swz = (n & 7) << 4;
#pragma unroll
        for (int j = 0; j < 8; ++j) {
            int c = kk + j * 8;
            float xv = bf2f(xr[c]);
            *(unsigned short*)(sp + ((rb + c * 2) ^ swz)) = f2bf(dt * xv);
            *(unsigned short*)(sp + ((rb + (c + 64) * 2) ^ swz)) = f2bf(bf2f(axr[c]) + xv);
        }
        *(unsigned short*)(sp + ((rb + (128 + kk) * 2) ^ swz)) =
            f2bf(bf2f(agg_eb[(size_t)i * 16 + kk]) + 1.0f);
        *(unsigned short*)(sp + ((rb + (136 + kk) * 2) ^ swz)) =
            f2bf(bf2f(agg_eb[(size_t)i * 16 + 8 + kk]) + 1.0f);
        *(unsigned short*)(sp + ((rb + (144 + kk) * 2) ^ swz)) = 0;
        *(unsigned short*)(sp + ((rb + (152 + kk) * 2) ^ swz)) = 0;
        if (kk == 0) sdeg[n] = dt;
    }
    __syncthreads();

    const int w = t >> 6, l = t & 63, lr = l & 15, lg = l >> 4;
    const int outc = w * 16 + lr;
    short8 bf[5];
    {
        const unsigned short* wp = Wl1 + (size_t)outc * 160 + lg * 8;
#pragma unroll
        for (int s = 0; s < 5; ++s) bf[s] = *(const short8*)(wp + s * 32);
    }
    const float bo = bias[outc];
    const float sc = bng[outc] * 0.99999500003749974f;  // 1/sqrt(1+1e-5)
    const float bb = bnb[outc];
#pragma unroll
    for (int ng = 0; ng < 4; ++ng) {
        int row = ng * 16 + lr, sw = (row & 7) << 4;
        short8 af[5];
#pragma unroll
        for (int s = 0; s < 5; ++s)
            af[s] = *(const short8*)((const char*)sA + ((row * 320 + s * 64 + lg * 16) ^ sw));
        f32x4 acc = {0.0f, 0.0f, 0.0f, 0.0f};
#pragma unroll
        for (int s = 0; s < 5; ++s)
            acc = __builtin_amdgcn_mfma_f32_16x16x32_bf16(af[s], bf[s], acc, 0, 0, 0);
#pragma unroll
        for (int r = 0; r < 4; ++r) {
            int node = ng * 16 + lg * 4 + r;
            float v = fmaxf(acc[r] + sdeg[node] * bo, 0.0f);
            v = fmaxf(v * sc + bb, 0.0f);
            if (base + node < N)
                h1[(size_t)(base + node) * 128 + outc] = f2bf(v);
        }
    }
}

// ---------------------------------------------------------------------------
// combine2 (MFMA, 64 nodes/block, 8 waves): same template, K=288, rows 576B.
// ---------------------------------------------------------------------------
__global__ __launch_bounds__(512) void combine2_kernel(
    const unsigned short* __restrict__ h1, const int* __restrict__ offs,
    const unsigned short* __restrict__ agg_eb, const unsigned short* __restrict__ agg_hb,
    const unsigned short* __restrict__ Wl2, const float* __restrict__ bias,
    const float* __restrict__ bng, const float* __restrict__ bnb,
    unsigned short* __restrict__ h2)
{
    __shared__ unsigned short sA[64 * 288];  // 36KB, rows of 576B
    __shared__ float sdeg[64];
    const int t = threadIdx.x;
    const int base = blockIdx.x * 64;
    {
        int n = t >> 3, kk = t & 7;
        int i = min(base + n, N - 1);
        float dt = (float)(offs[i + 1] - offs[i]) + 1.0f;
        const unsigned short* hr = h1 + (size_t)i * 128;
        const unsigned short* ahr = agg_hb + (size_t)i * 128;
        char* sp = (char*)sA;
        int rb = n * 576, swz = (n & 7) << 4;
#pragma unroll
        for (int j = 0; j < 16; ++j) {
            int c = kk + j * 8;
            float hv = bf2f(hr[c]);
            *(unsigned short*)(sp + ((rb + c * 2) ^ swz)) = f2bf(dt * hv);
            *(unsigned short*)(sp + ((rb + (c + 128) * 2) ^ swz)) = f2bf(bf2f(ahr[c]) + hv);
        }
        *(unsigned short*)(sp + ((rb + (256 + kk) * 2) ^ swz)) =
            f2bf(bf2f(agg_eb[(size_t)i * 16 + kk]) + 1.0f);
        *(unsigned short*)(sp + ((rb + (264 + kk) * 2) ^ swz)) =
            f2bf(bf2f(agg_eb[(size_t)i * 16 + 8 + kk]) + 1.0f);
        *(unsigned short*)(sp + ((rb + (272 + kk) * 2) ^ swz)) = 0;
        *(unsigned short*)(sp + ((rb + (280 + kk) * 2) ^ swz)) = 0;
        if (kk == 0) sdeg[n] = dt;
    }
    __syncthreads();

    const int w = t >> 6, l = t & 63, lr = l & 15, lg = l >> 4;
    const int outc = w * 16 + lr;
    short8 bf[9];
    {
        const unsigned short* wp = Wl2 + (size_t)outc * 288 + lg * 8;
#pragma unroll
        for (int s = 0; s < 9; ++s) bf[s] = *(const short8*)(wp + s * 32);
    }
    const float bo = bias[outc];
    const float sc = bng[outc] * 0.99999500003749974f;
    const float bb = bnb[outc];
#pragma unroll
    for (int ng = 0; ng < 4; ++ng) {
        int row = ng * 16 + lr, sw = (row & 7) << 4;
        short8 af[9];
#pragma unroll
        for (int s = 0; s < 9; ++s)
            af[s] = *(const short8*)((const char*)sA + ((row * 576 + s * 64 + lg * 16) ^ sw));
        f32x4 acc = {0.0f, 0.0f, 0.0f, 0.0f};
#pragma unroll
        for (int s = 0; s < 9; ++s)
            acc = __builtin_amdgcn_mfma_f32_16x16x32_bf16(af[s], bf[s], acc, 0, 0, 0);
#pragma unroll
        for (int r = 0; r < 4; ++r) {
            int node = ng * 16 + lg * 4 + r;
            float v = fmaxf(acc[r] + sdeg[node] * bo, 0.0f);
            v = fmaxf(v * sc + bb, 0.0f);
            if (base + node < N)
                h2[(size_t)(base + node) * 128 + outc] = f2bf(v);
        }
    }
}

// ---------------------------------------------------------------------------
// ge: deterministic global_add_pool. One block per graph (batch sorted).
// ---------------------------------------------------------------------------
__global__ __launch_bounds__(256) void ge_kernel(
    const unsigned short* __restrict__ h2, const int* __restrict__ gofs,
    float* __restrict__ ge)
{
    __shared__ float s[256];
    int g = blockIdx.x, t = threadIdx.x;
    int lo = gofs[g], hi = gofs[g + 1];
    int col = t & 127, half = t >> 7;
    float acc = 0.0f;
    for (int r = lo + half; r < hi; r += 2)
        acc += bf2f(h2[(size_t)r * 128 + col]);
    s[t] = acc;
    __syncthreads();
    if (t < 128) ge[(size_t)g * 128 + t] = s[t] + s[t + 128];
}

// ---------------------------------------------------------------------------
// final_mfma (64 nodes/block, 8 waves):
//   out = relu([h2 | ge[batch]]_bf16 @ Wt1^T + b1) @ Wt2^T + b2
// ---------------------------------------------------------------------------
__global__ __launch_bounds__(512) void final_mfma_kernel(
    const unsigned short* __restrict__ h2, const float* __restrict__ ge,
    const int* __restrict__ batch,
    const unsigned short* __restrict__ Wt1, const float* __restrict__ b1,
    const unsigned short* __restrict__ Wt2, const float* __restrict__ b2,
    float* __restrict__ out)
{
    __shared__ unsigned short sA[64 * 256];  // 32KB node_in, 512B rows swz'd
    __shared__ unsigned short sH[64 * 256];  // 32KB hidden
    const int t = threadIdx.x;
    const int base = blockIdx.x * 64;

    {   // stage node_in = [h2 | ge[batch]] as bf16, 8 threads/row
        int n = t >> 3, idx = t & 7;
        int i = min(base + n, N - 1);
        int rb = n * 512, swz = (n & 7) << 4;
        if (idx < 4) {
            const short8* hp = (const short8*)(h2 + (size_t)i * 128 + idx * 32);
#pragma unroll
            for (int q = 0; q < 4; ++q)
                *(short8*)((char*)sA + ((rb + idx * 64 + q * 16) ^ swz)) = hp[q];
        } else {
            const float4* gp = (const float4*)(ge + (size_t)batch[i] * 128 + (idx - 4) * 32);
#pragma unroll
            for (int q = 0; q < 4; ++q) {
                float4 a = gp[2 * q], b = gp[2 * q + 1];
                short8 c;
                c[0] = (short)f2bf(a.x); c[1] = (short)f2bf(a.y);
                c[2] = (short)f2bf(a.z); c[3] = (short)f2bf(a.w);
                c[4] = (short)f2bf(b.x); c[5] = (short)f2bf(b.y);
                c[6] = (short)f2bf(b.z); c[7] = (short)f2bf(b.w);
                *(short8*)((char*)sA + ((rb + 256 + (idx - 4) * 64 + q * 16) ^ swz)) = c;
            }
        }
    }
    __syncthreads();

    const int w = t >> 6, l = t & 63, lr = l & 15, lg = l >> 4;

    // ---- fc1 ----
#pragma unroll
    for (int tt = 0; tt < 2; ++tt) {
        int outc = (2 * w + tt) * 16 + lr;
        short8 bf[8];
        {
            const unsigned short* wp = Wt1 + (size_t)outc * 256 + lg * 8;
#pragma unroll
            for (int s = 0; s < 8; ++s) bf[s] = *(const short8*)(wp + s * 32);
        }
        float bb = b1[outc];
#pragma unroll
        for (int ng = 0; ng < 4; ++ng) {
            int row = ng * 16 + lr, sw = (row & 7) << 4;
            short8 af[8];
#pragma unroll
            for (int s = 0; s < 8; ++s)
                af[s] = *(const short8*)((const char*)sA + ((row * 512 + s * 64 + lg * 16) ^ sw));
            f32x4 acc = {0.0f, 0.0f, 0.0f, 0.0f};
#pragma unroll
            for (int s = 0; s < 8; ++s)
                acc = __builtin_amdgcn_mfma_f32_16x16x32_bf16(af[s], bf[s], acc, 0, 0, 0);
#pragma unroll
            for (int r = 0; r < 4; ++r) {
                int node = ng * 16 + lg * 4 + r;
                float hv = fmaxf(acc[r] + bb, 0.0f);
                int byte = (node * 512 + outc * 2) ^ ((node & 7) << 4);
                *(unsigned short*)((char*)sH + byte) = f2bf(hv);
            }
        }
    }
    __syncthreads();

    // ---- fc2 ----
    {
        int ct = w & 3, ngbase = (w >> 2) * 2;
        int outc = ct * 16 + lr;
        short8 bf[8];
        {
            const unsigned short* wp = Wt2 + (size_t)outc * 256 + lg * 8;
#pragma unroll
            for (int s = 0; s < 8; ++s) bf[s] = *(const short8*)(wp + s * 32);
        }
        float bb = b2[outc];
#pragma unroll
        for (int k = 0; k < 2; ++k) {
            int row = (ngbase + k) * 16 + lr, sw = (row & 7) << 4;
            short8 ah[8];
#pragma unroll
            for (int s = 0; s < 8; ++s)
                ah[s] = *(const short8*)((const char*)sH + ((row * 512 + s * 64 + lg * 16) ^ sw));
            f32x4 acc = {0.0f, 0.0f, 0.0f, 0.0f};
#pragma unroll
            for (int s = 0; s < 8; ++s)
                acc = __builtin_amdgcn_mfma_f32_16x16x32_bf16(ah[s], bf[s], acc, 0, 0, 0);
#pragma unroll
            for (int r = 0; r < 4; ++r) {
                int node = (ngbase + k) * 16 + lg * 4 + r;
                if (base + node < N)
                    out[(size_t)(base + node) * 64 + outc] = acc[r] + bb;
            }
        }
    }
}

// ---------------------------------------------------------------------------
extern "C" void kernel_launch(void* const* d_in, const int* in_sizes, int n_in,
                              void* d_out, int out_size, void* d_ws, size_t ws_size,
                              hipStream_t stream)
{
    const float* x      = (const float*)d_in[0];
    const int*   src    = (const int*)d_in[1];
    const int*   dst    = (const int*)d_in[2];
    const float* eattr  = (const float*)d_in[3];
    const int*   batch  = (const int*)d_in[4];
    const float* lin1_w = (const float*)d_in[5];
    const float* lin1_b = (const float*)d_in[6];
    const float* lin2_w = (const float*)d_in[7];
    const float* lin2_b = (const float*)d_in[8];
    const float* bn1_g  = (const float*)d_in[9];
    const float* bn1_b  = (const float*)d_in[10];
    const float* bn2_g  = (const float*)d_in[11];
    const float* bn2_b  = (const float*)d_in[12];
    const float* fc1_w  = (const float*)d_in[13];
    const float* fc1_b  = (const float*)d_in[14];
    const float* fc2_w  = (const float*)d_in[15];
    const float* fc2_b  = (const float*)d_in[16];
    float* out = (float*)d_out;

    // Workspace (~37 MB), no zeroing needed (every buffer fully written):
    //   bh | sc | bsum | boff | ge | gofs | offs | ssrc | seid | agg_eb |
    //   tmpreg (tmp int2 6.4MB during CSR build; agg_xb bf16 6.4MB after) |
    //   xb | agg_hb | h1 | h2 | Wl1 | Wl2 | Wt1 | Wt2
    char* p = (char*)d_ws;
    auto alloc = [&](size_t bytes) {
        char* r = p;
        p += (bytes + 15) & ~(size_t)15;
        return r;
    };
    int*   bh     = (int*)alloc((size_t)4 * SC_N);
    int*   sc     = (int*)alloc((size_t)4 * SC_N);
    int*   bsum   = (int*)alloc((size_t)4 * SCB);
    int*   boff   = (int*)alloc((size_t)4 * SCB);
    float* ge     = (float*)alloc((size_t)512 * G);
    int*   gofs   = (int*)alloc((size_t)4 * (G + 1));
    int*   offs   = (int*)alloc((size_t)4 * (N + 1));
    int*   ssrc   = (int*)alloc((size_t)4 * E);
    int*   seid   = (int*)alloc((size_t)4 * E);
    unsigned short* agg_eb = (unsigned short*)alloc((size_t)32 * N);
    char*  tmpreg = alloc((size_t)8 * E);             // 6.4 MB
    int2*  tmp    = (int2*)tmpreg;                    // CSR-build phase
    unsigned short* agg_xb = (unsigned short*)tmpreg; // 128B/node, after sort
    unsigned short* xb     = (unsigned short*)alloc((size_t)128 * N);
    unsigned*       agg_hb = (unsigned*)alloc((size_t)256 * N);
    unsigned short* h1  = (unsigned short*)alloc((size_t)256 * N);
    unsigned short* h2  = (unsigned short*)alloc((size_t)256 * N);
    unsigned short* Wl1 = (unsigned short*)alloc(2 * 20480);
    unsigned short* Wl2 = (unsigned short*)alloc(2 * 36864);
    unsigned short* Wt1 = (unsigned short*)alloc(2 * 65536);
    unsigned short* Wt2 = (unsigned short*)alloc(2 * 16384);

    // --- CSR build: block-local 3-phase counting sort + weight prep ---
    hist_xconv_kernel<<<NBLK, 256, 0, stream>>>(dst, x, bh, xb);
    scan_bsum_kernel<<<SCB, 256, 0, stream>>>(bh, bsum);
    scan_partials_kernel<<<1, 256, 0, stream>>>(bsum, boff);
    scan_write_kernel<<<SCB, 256, 0, stream>>>(bh, boff, sc);
    scatter_kernel<<<NBLK, 256, 0, stream>>>(src, dst, sc, tmp);
    bucket_sort_kernel<<<NBUCK, 512, 0, stream>>>(tmp, sc, ssrc, seid, offs);
    prep_weights_kernel<<<549, 256, 0, stream>>>(lin1_w, lin2_w, fc1_w, fc2_w,
                                                 batch, Wl1, Wl2, Wt1, Wt2, gofs);

    const int NB64 = (N + 63) / 64;   // 782
    const int NB4  = (N + 3) / 4;     // 12500

    // --- Layer 1 ---
    gather1_kernel<<<NB4, 256, 0, stream>>>(xb, eattr, ssrc, seid, offs,
                                            agg_xb, agg_eb);
    combine1_kernel<<<NB64, 512, 0, stream>>>(xb, offs, agg_eb, agg_xb,
                                              Wl1, lin1_b, bn1_g, bn1_b, h1);

    // --- Layer 2 ---
    gather2_kernel<<<NB4, 256, 0, stream>>>(h1, ssrc, offs, agg_hb);
    combine2_kernel<<<NB64, 512, 0, stream>>>(h1, offs, agg_eb,
                                              (const unsigned short*)agg_hb,
                                              Wl2, lin2_b, bn2_g, bn2_b, h2);

    // --- Pool + readout ---
    ge_kernel<<<G, 256, 0, stream>>>(h2, gofs, ge);
    final_mfma_kernel<<<NB64, 512, 0, stream>>>(h2, ge, batch,
                                                Wt1, fc1_b, Wt2, fc2_b, out);
}